// Round 6
// baseline (280.189 us; speedup 1.0000x reference)
//
#include <hip/hip_runtime.h>
#include <hip/hip_bf16.h>

typedef __attribute__((ext_vector_type(8))) short short8;
typedef __attribute__((ext_vector_type(4))) float f32x4;
typedef __attribute__((ext_vector_type(16))) float f32x16;
typedef __attribute__((ext_vector_type(2))) unsigned int uint2v;
typedef __attribute__((ext_vector_type(4))) unsigned int uint4v;

#define SEQ    2048
#define DM     1024
#define NH     16
#define DH     64
#define NBATCH 4
#define MTOK   (NBATCH * SEQ)                       // 8192 tokens
#define SEG    ((size_t)NBATCH * NH * SEQ * DH)     // 8388608 elems per Q/K/V buffer
// Q pre-scaled by 1/sqrt(64) * log2(e) so attention inner loop is exp2 only.
#define QSCALE 0.18033688f

// Fast RNE float->bf16 for FINITE values: bf16 bits land in the high 16.
static __device__ __forceinline__ unsigned bfbits(float f) {
  unsigned u = __float_as_uint(f);
  return u + 0x7fffu + ((u >> 16) & 1u);
}
static __device__ __forceinline__ unsigned short f2bf(float f) {
  return (unsigned short)(bfbits(f) >> 16);
}
// RNE pack of two floats to packed bf16x2 (lo in low half).
static __device__ __forceinline__ unsigned pack2bf(float lo, float hi) {
  return __builtin_amdgcn_perm(bfbits(hi), bfbits(lo), 0x07060302u);
}
// Truncation pack (round-toward-zero for positives): 1 v_perm on raw bits.
static __device__ __forceinline__ unsigned pack2tr(unsigned ulo, unsigned uhi) {
  return __builtin_amdgcn_perm(uhi, ulo, 0x07060302u);
}

typedef const __attribute__((address_space(1))) unsigned int* gp_t;
typedef __attribute__((address_space(3))) unsigned int* lp_t;
static __device__ __forceinline__ void gload_lds16(const void* g, void* l) {
  __builtin_amdgcn_global_load_lds((gp_t)g, (lp_t)l, 16, 0, 0);
}

// ---------------------------------------------------------------------------
// Fused prep: xcast (fp32->bf16, 8 elems/thread) + both weight transposes
// (W [K][N] fp32 -> WT [N][K] bf16, 64x64 tiles) in ONE dispatch.
// Block roles by blockIdx range: [0,4096) xcast, [4096,4864) Wqkv, rest Wo.
// ---------------------------------------------------------------------------
template <bool WITH_X>
__global__ __launch_bounds__(256) void prep_kernel(
    const float* __restrict__ x, unsigned short* __restrict__ xb,
    const float* __restrict__ Wqkv, unsigned short* __restrict__ WqT,
    const float* __restrict__ Wo, unsigned short* __restrict__ WoT) {
  __shared__ float T[64][65];
  const int tid = threadIdx.x;
  int bid = blockIdx.x;
  if (WITH_X) {
    if (bid < 4096) {
      size_t i = ((size_t)bid * 256 + tid) * 8;
      f32x4 a = *(const f32x4*)&x[i];
      f32x4 b = *(const f32x4*)&x[i + 4];
      uint4v s;
      s[0] = pack2bf(a[0], a[1]);
      s[1] = pack2bf(a[2], a[3]);
      s[2] = pack2bf(b[0], b[1]);
      s[3] = pack2bf(b[2], b[3]);
      *(uint4v*)&xb[i] = s;
      return;
    }
    bid -= 4096;
  }
  const float* W;
  unsigned short* WT;
  int N, n0, k0;
  if (bid < 768) {  // Wqkv: [1024][3072], 48 x 16 tiles
    W = Wqkv; WT = WqT; N = 3 * DM;
    n0 = (bid % 48) * 64; k0 = (bid / 48) * 64;
  } else {          // Wo: [1024][1024], 16 x 16 tiles
    bid -= 768;
    W = Wo; WT = WoT; N = DM;
    n0 = (bid % 16) * 64; k0 = (bid / 16) * 64;
  }
#pragma unroll
  for (int it = 0; it < 4; it++) {
    int row = it * 16 + (tid >> 4);
    int c4 = (tid & 15) * 4;
    f32x4 v = *(const f32x4*)&W[(size_t)(k0 + row) * N + n0 + c4];
#pragma unroll
    for (int j = 0; j < 4; j++) T[row][c4 + j] = v[j];
  }
  __syncthreads();
#pragma unroll
  for (int it = 0; it < 2; it++) {
    int chunk = tid + it * 256;
    int n = chunk >> 3;
    int c8 = (chunk & 7) * 8;
    uint4v s;
#pragma unroll
    for (int j = 0; j < 4; j++)
      s[j] = pack2bf(T[c8 + 2 * j][n], T[c8 + 2 * j + 1][n]);
    *(uint4v*)&WT[(size_t)(n0 + n) * DM + k0 + c8] = s;
  }
}

// ---------------------------------------------------------------------------
// 256x256 deep-pipelined GEMM for QKV: C[M,N] = A[M,K] @ BT[N,K]^T.
// 512 threads = 8 waves (2 wr x 4 wc); per-wave output 128x64 (acc[8][4]).
// LDS: 2-buffer ring, 128 KiB. Granule-XOR swizzle as in the 128 kernel.
// Ring schedule (T4 counted-vmcnt, never 0 in steady state):
//   prologue: stage(t0->b0), stage(t1->b1), vmcnt(8) [t0 resident], barrier
//   loop t:   compute(t) [24 ds_read_b128 + 64 MFMA/wave, compiler-sched]
//             lgkmcnt(0), barrier        // all waves done READING buf(t&1)
//             stage(t+2 -> buf(t&1))     // 8 loads into freed buffer
//             vmcnt(8), barrier          // tile t+1 resident; t+2 in flight
// -> staged loads get a full 64-MFMA phase (~600 cy) to land; the barrier
// never drains the fresh prefetch. QKV scatter epilogue (V transposed).
// Ring invariant audit (r6): barriers uniform (t,NKT wave-uniform); vmcnt(8)
// after stage retires exactly the 8 older tile-(t+1) loads; tails
// (t+2==NKT -> vmcnt(0); last iter -> no sync) verified.
// ---------------------------------------------------------------------------
__global__ __launch_bounds__(512, 2) void gemm256_qkv(
    const unsigned short* __restrict__ A, const unsigned short* __restrict__ BT,
    unsigned short* __restrict__ out0, unsigned short* __restrict__ out1,
    unsigned short* __restrict__ out2, int M, int N, int K) {
  __shared__ unsigned short As[2][256][64];
  __shared__ unsigned short Bs[2][256][64];

  const int tid = threadIdx.x;
  const int wave = tid >> 6;
  const int lane = tid & 63;
  const int quad = lane >> 4;
  const int lc = lane & 15;
  const int wr = wave >> 2;             // 0..1
  const int wc = wave & 3;              // 0..3
  const int m0 = blockIdx.y * 256;
  const int n0 = blockIdx.x * 256;
  const int xsw = lc & 7;               // fragment-read swizzle key
  const int lr8 = lane >> 3;            // staging: row within 8-row group
  const int sgo = ((lane & 7) ^ (lr8 & 7)) * 8;  // swizzled source offset

  f32x4 acc[8][4];
#pragma unroll
  for (int i = 0; i < 8; i++)
#pragma unroll
    for (int j = 0; j < 4; j++) acc[i][j] = (f32x4){0.f, 0.f, 0.f, 0.f};

  const int NKT = K >> 6;

  auto stage = [&](int k0s, int buf) {
    // 8 gload_lds/wave: A rows [0,256) + B rows [0,256), 64 rows per issue-pair.
#pragma unroll
    for (int i = 0; i < 4; i++) {
      int rbase = i * 64 + wave * 8;
      gload_lds16(&A[(size_t)(m0 + rbase + lr8) * K + k0s + sgo],
                  &As[buf][rbase][0]);
      gload_lds16(&BT[(size_t)(n0 + rbase + lr8) * K + k0s + sgo],
                  &Bs[buf][rbase][0]);
    }
  };

  stage(0, 0);
  if (NKT > 1) stage(64, 1);
  asm volatile("s_waitcnt vmcnt(8)" ::: "memory");
  __builtin_amdgcn_sched_barrier(0);
  __builtin_amdgcn_s_barrier();
  __builtin_amdgcn_sched_barrier(0);

  for (int t = 0; t < NKT; t++) {
    const int cur = t & 1;
    // B fragments: 4 nt x 2 kc (32 VGPR live).
    short8 bB[4][2];
#pragma unroll
    for (int nt = 0; nt < 4; nt++)
#pragma unroll
      for (int kc = 0; kc < 2; kc++)
        bB[nt][kc] = *(const short8*)&Bs[cur][wc * 64 + nt * 16 + lc]
                                        [((kc * 4 + quad) ^ xsw) * 8];
    // Two m-halves of 4 mt each: 8 A-reads then 16 MFMA per half.
#pragma unroll
    for (int mh = 0; mh < 2; mh++) {
      short8 aA[4][2];
#pragma unroll
      for (int m4 = 0; m4 < 4; m4++)
#pragma unroll
        for (int kc = 0; kc < 2; kc++)
          aA[m4][kc] = *(const short8*)&As[cur][wr * 128 + (mh * 4 + m4) * 16 + lc]
                                          [((kc * 4 + quad) ^ xsw) * 8];
      __builtin_amdgcn_s_setprio(1);
#pragma unroll
      for (int m4 = 0; m4 < 4; m4++)
#pragma unroll
        for (int nt = 0; nt < 4; nt++)
#pragma unroll
          for (int kc = 0; kc < 2; kc++)
            acc[mh * 4 + m4][nt] = __builtin_amdgcn_mfma_f32_16x16x32_bf16(
                aA[m4][kc], bB[nt][kc], acc[mh * 4 + m4][nt], 0, 0, 0);
      __builtin_amdgcn_s_setprio(0);
    }

    if (t + 1 < NKT) {
      // All waves finished reading buf(cur) -> safe to overwrite.
      asm volatile("s_waitcnt lgkmcnt(0)" ::: "memory");
      __builtin_amdgcn_sched_barrier(0);
      __builtin_amdgcn_s_barrier();
      __builtin_amdgcn_sched_barrier(0);
      if (t + 2 < NKT) {
        stage((t + 2) * 64, cur);
        asm volatile("s_waitcnt vmcnt(8)" ::: "memory");  // t+1 resident
      } else {
        asm volatile("s_waitcnt vmcnt(0)" ::: "memory");  // last tile resident
      }
      __builtin_amdgcn_sched_barrier(0);
      __builtin_amdgcn_s_barrier();
      __builtin_amdgcn_sched_barrier(0);
    }
  }

  // Epilogue: C/D layout col=lane&15, row=quad*4+reg. QKV scatter.
  const int c = n0 >> 10;  // segment (block-uniform): 0=Q 1=K 2=V
#pragma unroll
  for (int mt = 0; mt < 8; mt++)
#pragma unroll
    for (int nt = 0; nt < 4; nt++) {
      int rb = m0 + wr * 128 + mt * 16 + quad * 4;  // 4 consecutive tokens
      int col = n0 + wc * 64 + nt * 16 + lc;
      int rem = col & 1023;
      int h = rem >> 6;
      int dd = rem & 63;
      int b = rb >> 11;
      int tt = rb & 2047;
      if (c == 2) {
        uint2v pk;
        pk[0] = pack2bf(acc[mt][nt][0], acc[mt][nt][1]);
        pk[1] = pack2bf(acc[mt][nt][2], acc[mt][nt][3]);
        *(uint2v*)&out2[(((size_t)(b * NH + h)) * DH + dd) * SEQ + tt] = pk;
      } else {
        unsigned short* dst = (c == 0) ? out0 : out1;
        float sc = (c == 0) ? QSCALE : 1.0f;
#pragma unroll
        for (int r = 0; r < 4; r++)
          dst[(((size_t)(b * NH + h) * SEQ + tt + r) << 6) + dd] =
              f2bf(acc[mt][nt][r] * sc);
      }
    }
}

// ---------------------------------------------------------------------------
// 128x128 GEMM (round-3 single-buffer form): C = A @ BT^T, fp32 accum.
// 256 threads (4 waves 2x2), granule-XOR swizzle, two barriers per K-step.
// MODE 0: A fp32 (VALU cvt staging); QKV scatter epilogue (fallback path).
// MODE 1: A bf16 (DMA staging);      fp32 row-major output (Wo GEMM).
// ---------------------------------------------------------------------------
template <int MODE>
__global__ __launch_bounds__(256) void gemm_kernel(
    const void* __restrict__ Av, const unsigned short* __restrict__ BT,
    unsigned short* __restrict__ out0, unsigned short* __restrict__ out1,
    unsigned short* __restrict__ out2, float* __restrict__ outf,
    int M, int N, int K) {
  __shared__ unsigned short As[128][64];
  __shared__ unsigned short Bs[128][64];

  const int tid = threadIdx.x;
  const int wave = tid >> 6;
  const int lane = tid & 63;
  const int quad = lane >> 4;
  const int lc = lane & 15;
  const int wr = wave >> 1;
  const int wc = wave & 1;
  const int m0 = blockIdx.y * 128;
  const int n0 = blockIdx.x * 128;
  const int xsw = lc & 7;               // fragment-read swizzle key
  const int lr8 = lane >> 3;            // staging: row within 8-row group
  const int sgo = ((lane & 7) ^ (lr8 & 7)) * 8;  // swizzled source offset

  f32x4 acc[4][4];
#pragma unroll
  for (int i = 0; i < 4; i++)
#pragma unroll
    for (int j = 0; j < 4; j++) acc[i][j] = (f32x4){0.f, 0.f, 0.f, 0.f};

  for (int k0 = 0; k0 < K; k0 += 64) {
    // ---- Stage A tile (128 x 64) ----
    if (MODE == 0) {
      const float* A = (const float*)Av;
#pragma unroll
      for (int i = 0; i < 4; i++) {
        int chunk = tid + i * 256;      // 1024 granules
        int r = chunk >> 3;
        int g = chunk & 7;
        int scol = (g ^ (r & 7)) * 8;
        f32x4 v0 = *(const f32x4*)&A[(size_t)(m0 + r) * K + k0 + scol];
        f32x4 v1 = *(const f32x4*)&A[(size_t)(m0 + r) * K + k0 + scol + 4];
        uint4v s;
        s[0] = pack2bf(v0[0], v0[1]);
        s[1] = pack2bf(v0[2], v0[3]);
        s[2] = pack2bf(v1[0], v1[1]);
        s[3] = pack2bf(v1[2], v1[3]);
        *(uint4v*)&As[r][g * 8] = s;
      }
    } else {
      const unsigned short* A = (const unsigned short*)Av;
#pragma unroll
      for (int it = 0; it < 4; it++) {
        int rbase = wave * 32 + it * 8;  // 8 rows = 1 KB per instruction
        gload_lds16(&A[(size_t)(m0 + rbase + lr8) * K + k0 + sgo],
                    &As[rbase][0]);
      }
    }
    // ---- Stage B tile (128 n-rows x 64 k) ----
#pragma unroll
    for (int it = 0; it < 4; it++) {
      int rbase = wave * 32 + it * 8;
      gload_lds16(&BT[(size_t)(n0 + rbase + lr8) * K + k0 + sgo],
                  &Bs[rbase][0]);
    }
    __syncthreads();

#pragma unroll
    for (int kc = 0; kc < 2; kc++) {
      short8 aA[4], bB[4];
#pragma unroll
      for (int mt = 0; mt < 4; mt++)
        aA[mt] = *(const short8*)&As[wr * 64 + mt * 16 + lc]
                                    [((kc * 4 + quad) ^ xsw) * 8];
#pragma unroll
      for (int nt = 0; nt < 4; nt++)
        bB[nt] = *(const short8*)&Bs[wc * 64 + nt * 16 + lc]
                                    [((kc * 4 + quad) ^ xsw) * 8];
#pragma unroll
      for (int mt = 0; mt < 4; mt++)
#pragma unroll
        for (int nt = 0; nt < 4; nt++)
          acc[mt][nt] = __builtin_amdgcn_mfma_f32_16x16x32_bf16(
              aA[mt], bB[nt], acc[mt][nt], 0, 0, 0);
    }
    __syncthreads();
  }

  // Epilogue: C/D layout col=lane&15, row=quad*4+reg.
  const int c = n0 >> 10;  // QKV segment (block-uniform): 0=Q 1=K 2=V
#pragma unroll
  for (int mt = 0; mt < 4; mt++)
#pragma unroll
    for (int nt = 0; nt < 4; nt++) {
      int rb = m0 + wr * 64 + mt * 16 + quad * 4;  // 4 consecutive tokens
      int col = n0 + wc * 64 + nt * 16 + lc;
      if (MODE == 1) {
#pragma unroll
        for (int r = 0; r < 4; r++)
          outf[(size_t)(rb + r) * N + col] = acc[mt][nt][r];
      } else {
        int rem = col & 1023;
        int h = rem >> 6;
        int dd = rem & 63;
        int b = rb >> 11;
        int tt = rb & 2047;
        if (c == 2) {
          uint2v pk;
          pk[0] = pack2bf(acc[mt][nt][0], acc[mt][nt][1]);
          pk[1] = pack2bf(acc[mt][nt][2], acc[mt][nt][3]);
          *(uint2v*)&out2[(((size_t)(b * NH + h)) * DH + dd) * SEQ + tt] = pk;
        } else {
          unsigned short* dst = (c == 0) ? out0 : out1;
          float sc = (c == 0) ? QSCALE : 1.0f;
#pragma unroll
          for (int r = 0; r < 4; r++)
            dst[(((size_t)(b * NH + h) * SEQ + tt + r) << 6) + dd] =
                f2bf(acc[mt][nt][r] * sc);
        }
      }
    }
}

// ---------------------------------------------------------------------------
// Flash attention. Q,K: [bh][T][64] bf16 (Q pre-scaled); Vt: [bh][64][T] bf16.
// Block = 256 thr = 4 waves; wave owns 32 q-rows (block 128); 64-key tiles.
// S^T = K·Q^T via 32x32x16 MFMA -> 4 consecutive keys per lane. P packed by
// TRUNCATION; half-exchange via v_permlane32_swap_b32; l via MFMA ride-along
// (o_l = P·ones, same truncated fragments -> self-consistent). K/Vt
// double-buffered; XCD-aware grid (each XCD owns 8 heads; FETCH 24.6 MB).
// VGPR diet + __launch_bounds__(256,4) -> 56 VGPR, 84.5 us (round 3).
// ---------------------------------------------------------------------------
__global__ __launch_bounds__(256, 4) void attn_kernel(
    const unsigned short* __restrict__ Q, const unsigned short* __restrict__ K,
    const unsigned short* __restrict__ Vt, unsigned short* __restrict__ ctx) {
  __shared__ unsigned short KsL[2][64 * 64];  // granule-swizzled [key][d]
  __shared__ unsigned short VtL[2][64 * 64];  // granule-swizzled [d][key]

  const int tid = threadIdx.x;
  const int wave = tid >> 6;
  const int lane = tid & 63;
  const int half = lane >> 5;
  const int l31 = lane & 31;
  // XCD swizzle: dispatch order round-robins XCDs (id%8). Give each XCD 8
  // consecutive heads so all 16 q-tiles of a head share one L2.
  const int id = blockIdx.x;
  const int bh = (id & 7) * 8 + (id >> 3) / 16;
  const int qt = (id >> 3) & 15;
  const int q0 = qt * 128 + wave * 32;
  const unsigned kqbase = (unsigned)bh * (SEQ * DH);  // offsets fit 32-bit
  const unsigned vbase = (unsigned)bh * (DH * SEQ);

  // Q B-fragments (n=qrow=l31, k=d): 4 d-chunks of 16.
  short8 bQ[4];
#pragma unroll
  for (int dc = 0; dc < 4; dc++)
    bQ[dc] = *(const short8*)&Q[kqbase + (unsigned)(q0 + l31) * DH + dc * 16 + half * 8];

  f32x16 o[2], o_l;
#pragma unroll
  for (int nb = 0; nb < 2; nb++)
#pragma unroll
    for (int j = 0; j < 16; j++) o[nb][j] = 0.f;
#pragma unroll
  for (int j = 0; j < 16; j++) o_l[j] = 0.f;

  // All-ones bf16 B fragment for the l ride-along MFMA.
  union { unsigned u[4]; short8 s8; } onesu;
#pragma unroll
  for (int j = 0; j < 4; j++) onesu.u[j] = 0x3f803f80u;
  const short8 ones = onesu.s8;

  const int xsw = l31 & 7;  // bank-swizzle key for this lane's fragment rows
  // Hoisted staging geometry (granule id = wave*128 + it*64 + lane).
  // Second issue of each pair is +8 rows: same swizzle ((g0+64)&7 == g0&7,
  // (r0+8)&7 == r0&7) -> derive by constant add, no extra registers.
  const int g0 = wave * 128 + lane;
  const int r0 = g0 >> 3;
  const unsigned sgo = ((g0 & 7) ^ (r0 & 7)) * 8;
  const unsigned so0 = (unsigned)r0 * DH + sgo;
  const unsigned sv0 = (unsigned)r0 * SEQ + sgo;
  const int ldo = wave * 1024;  // this wave's staging region (shorts)

  auto stage = [&](int kt, int b) {
    const unsigned kg = kqbase + (unsigned)kt * (64 * DH);
    const unsigned vg = vbase + (unsigned)kt * 64;
    unsigned short* kd = &KsL[b][ldo];
    unsigned short* vd = &VtL[b][ldo];
    gload_lds16(&K[kg + so0], kd);
    gload_lds16(&K[kg + so0 + 8 * DH], kd + 512);
    gload_lds16(&Vt[vg + sv0], vd);
    gload_lds16(&Vt[vg + sv0 + 8 * SEQ], vd + 512);
  };

  stage(0, 0);
  __syncthreads();

  for (int kt = 0; kt < SEQ / 64; kt++) {
    const int cur = kt & 1;
    if (kt + 1 < SEQ / 64) stage(kt + 1, cur ^ 1);  // prefetch next tile
    const unsigned short* kcur = &KsL[cur][0];
    const unsigned short* vcur = &VtL[cur][0];

    // S^T = K·Q^T : two 32-key blocks, contraction d=64 (4 chained MFMA),
    // then softmax+pack and P·V for that key-block (in-register exchange).
#pragma unroll
    for (int kb = 0; kb < 2; kb++) {
      f32x16 s;
#pragma unroll
      for (int j = 0; j < 16; j++) s[j] = 0.f;
      __builtin_amdgcn_s_setprio(1);
#pragma unroll
      for (int dc = 0; dc < 4; dc++) {
        const short8 aK = *(const short8*)&kcur[(unsigned)(kb * 32 + l31) * 64 +
                                                ((dc * 2 + half) ^ xsw) * 8];
        s = __builtin_amdgcn_mfma_f32_32x32x16_bf16(aK, bQ[dc], s, 0, 0, 0);
      }
      __builtin_amdgcn_s_setprio(0);

      // p = exp2(s); truncate to bf16 (pack is 1 v_perm per pair).
      // Lane (l31,half) holds keys kb*32 + gq*8 + half*4 + {0..3} as packed
      // dwords d0[gq] (keys +0,1) and d1[gq] (keys +2,3).
      unsigned d0[4], d1[4];
#pragma unroll
      for (int gq = 0; gq < 4; gq++) {
        unsigned u0 = __float_as_uint(__builtin_amdgcn_exp2f(s[gq * 4 + 0]));
        unsigned u1 = __float_as_uint(__builtin_amdgcn_exp2f(s[gq * 4 + 1]));
        unsigned u2 = __float_as_uint(__builtin_amdgcn_exp2f(s[gq * 4 + 2]));
        unsigned u3 = __float_as_uint(__builtin_amdgcn_exp2f(s[gq * 4 + 3]));
        d0[gq] = pack2tr(u0, u1);
        d1[gq] = pack2tr(u2, u3);
      }

      // O += P·V for this 32-key block: chunks kc = kb*2 + {0,1}.
      // A-fragment dwords for chunk: w0..w3 = keys chunk*16 + half*8 + pairs.
      // v_permlane32_swap_b32 exchanges a.hi-lanes with b.lo-lanes:
      //   swap(d0[2k], d0[2k+1]) -> (w0, w2); swap(d1[2k], d1[2k+1]) -> (w1, w3).
      // l rides along as o_l = P·ones (same A fragments, same truncation ->
      // exactly self-consistent normalization, zero VALU cost).
#pragma unroll
      for (int kcl = 0; kcl < 2; kcl++) {
        unsigned w0 = d0[kcl * 2], w2 = d0[kcl * 2 + 1];
        unsigned w1 = d1[kcl * 2], w3 = d1[kcl * 2 + 1];
        asm("v_permlane32_swap_b32 %0, %1" : "+v"(w0), "+v"(w2));
        asm("v_permlane32_swap_b32 %0, %1" : "+v"(w1), "+v"(w3));
        union { unsigned u[4]; short8 s8; } cv;
        cv.u[0] = w0; cv.u[1] = w1; cv.u[2] = w2; cv.u[3] = w3;
        const int kc = kb * 2 + kcl;
        __builtin_amdgcn_s_setprio(1);
#pragma unroll
        for (int nb = 0; nb < 2; nb++) {
          const short8 bV = *(const short8*)&vcur[(unsigned)(nb * 32 + l31) * 64 +
                                                  ((kc * 2 + half) ^ xsw) * 8];
          o[nb] = __builtin_amdgcn_mfma_f32_32x32x16_bf16(cv.s8, bV, o[nb], 0, 0, 0);
        }
        o_l = __builtin_amdgcn_mfma_f32_32x32x16_bf16(cv.s8, ones, o_l, 0, 0, 0);
        __builtin_amdgcn_s_setprio(0);
      }
    }
    __syncthreads();  // staged next tile complete; buffers free for overwrite
  }

  // Epilogue: o_l rows align with o rows (same A-op, same MFMA shape), so
  // normalization is purely lane-local. ctx write coalesced over l31.
  const int b = bh >> 4;
  const int h = bh & 15;
#pragma unroll
  for (int gq = 0; gq < 4; gq++)
#pragma unroll
    for (int j = 0; j < 4; j++) {
      int r = gq * 4 + j;
      int ql = j + gq * 8 + half * 4;  // q within wave (C-layout row)
      float inv = __builtin_amdgcn_rcpf(o_l[r]);
      int token = qt * 128 + wave * 32 + ql;
#pragma unroll
      for (int nb = 0; nb < 2; nb++)
        ctx[((size_t)b * SEQ + token) * DM + h * DH + nb * 32 + l31] =
            f2bf(o[nb][r] * inv);
    }
}

extern "C" void kernel_launch(void* const* d_in, const int* in_sizes, int n_in,
                              void* d_out, int out_size, void* d_ws,
                              size_t ws_size, hipStream_t stream) {
  const float* x = (const float*)d_in[0];     // [8192,1024] fp32
  const float* Wqkv = (const float*)d_in[1];  // [1024,3072] fp32
  const float* Wo = (const float*)d_in[2];    // [1024,1024] fp32
  float* out = (float*)d_out;                 // [8192,1024] fp32
  unsigned short* ws = (unsigned short*)d_ws;

  unsigned short* Qb = ws;                          // [bh][T][64], pre-scaled
  unsigned short* Kb = ws + SEG;                    // [bh][T][64]
  unsigned short* Vt = ws + 2 * SEG;                // [bh][64][T]
  unsigned short* Ctx = ws + 3 * SEG;               // [8192][1024]
  unsigned short* WqT = Ctx + (size_t)MTOK * DM;    // [3072][1024]
  unsigned short* WoT = WqT + (size_t)3 * DM * DM;  // [1024][1024]
  unsigned short* Xb = WoT + (size_t)DM * DM;       // [8192][1024]
  const size_t need =
      ((size_t)(Xb - ws) + (size_t)MTOK * DM) * sizeof(unsigned short);

  if (ws_size >= need) {
    prep_kernel<true><<<dim3(4096 + 768 + 256), 256, 0, stream>>>(
        x, Xb, Wqkv, WqT, Wo, WoT);
    gemm256_qkv<<<dim3(3 * DM / 256, MTOK / 256), 512, 0, stream>>>(
        Xb, WqT, Qb, Kb, Vt, MTOK, 3 * DM, DM);
  } else {
    prep_kernel<false><<<dim3(768 + 256), 256, 0, stream>>>(
        x, nullptr, Wqkv, WqT, Wo, WoT);
    gemm_kernel<0><<<dim3(3 * DM / 128, MTOK / 128), 256, 0, stream>>>(
        (const void*)x, WqT, Qb, Kb, Vt, nullptr, MTOK, 3 * DM, DM);
  }
  attn_kernel<<<dim3(SEQ / 128 * NBATCH * NH), 256, 0, stream>>>(Qb, Kb, Vt, Ctx);
  gemm_kernel<1><<<dim3(DM / 128, MTOK / 128), 256, 0, stream>>>(
      (const void*)Ctx, WoT, nullptr, nullptr, nullptr, out, MTOK, DM, DM);
}

// Round 7
// 259.676 us; speedup vs baseline: 1.0790x; 1.0790x over previous
//
#include <hip/hip_runtime.h>
#include <hip/hip_bf16.h>

typedef __attribute__((ext_vector_type(8))) short short8;
typedef __attribute__((ext_vector_type(4))) float f32x4;
typedef __attribute__((ext_vector_type(16))) float f32x16;
typedef __attribute__((ext_vector_type(2))) unsigned int uint2v;
typedef __attribute__((ext_vector_type(4))) unsigned int uint4v;

#define SEQ    2048
#define DM     1024
#define NH     16
#define DH     64
#define NBATCH 4
#define MTOK   (NBATCH * SEQ)                       // 8192 tokens
#define SEG    ((size_t)NBATCH * NH * SEQ * DH)     // 8388608 elems per Q/K/V buffer
// Q pre-scaled by 1/sqrt(64) * log2(e) so attention inner loop is exp2 only.
#define QSCALE 0.18033688f

// Fast RNE float->bf16 for FINITE values: bf16 bits land in the high 16.
static __device__ __forceinline__ unsigned bfbits(float f) {
  unsigned u = __float_as_uint(f);
  return u + 0x7fffu + ((u >> 16) & 1u);
}
static __device__ __forceinline__ unsigned short f2bf(float f) {
  return (unsigned short)(bfbits(f) >> 16);
}
// RNE pack of two floats to packed bf16x2 (lo in low half).
static __device__ __forceinline__ unsigned pack2bf(float lo, float hi) {
  return __builtin_amdgcn_perm(bfbits(hi), bfbits(lo), 0x07060302u);
}
// Truncation pack (round-toward-zero for positives): 1 v_perm on raw bits.
static __device__ __forceinline__ unsigned pack2tr(unsigned ulo, unsigned uhi) {
  return __builtin_amdgcn_perm(uhi, ulo, 0x07060302u);
}

typedef const __attribute__((address_space(1))) unsigned int* gp_t;
typedef __attribute__((address_space(3))) unsigned int* lp_t;
static __device__ __forceinline__ void gload_lds16(const void* g, void* l) {
  __builtin_amdgcn_global_load_lds((gp_t)g, (lp_t)l, 16, 0, 0);
}

// ---------------------------------------------------------------------------
// Fused prep: xcast (fp32->bf16, 8 elems/thread) + both weight transposes
// (W [K][N] fp32 -> WT [N][K] bf16, 64x64 tiles) in ONE dispatch.
// Block roles by blockIdx range: [0,4096) xcast, [4096,4864) Wqkv, rest Wo.
// ---------------------------------------------------------------------------
template <bool WITH_X>
__global__ __launch_bounds__(256) void prep_kernel(
    const float* __restrict__ x, unsigned short* __restrict__ xb,
    const float* __restrict__ Wqkv, unsigned short* __restrict__ WqT,
    const float* __restrict__ Wo, unsigned short* __restrict__ WoT) {
  __shared__ float T[64][65];
  const int tid = threadIdx.x;
  int bid = blockIdx.x;
  if (WITH_X) {
    if (bid < 4096) {
      size_t i = ((size_t)bid * 256 + tid) * 8;
      f32x4 a = *(const f32x4*)&x[i];
      f32x4 b = *(const f32x4*)&x[i + 4];
      uint4v s;
      s[0] = pack2bf(a[0], a[1]);
      s[1] = pack2bf(a[2], a[3]);
      s[2] = pack2bf(b[0], b[1]);
      s[3] = pack2bf(b[2], b[3]);
      *(uint4v*)&xb[i] = s;
      return;
    }
    bid -= 4096;
  }
  const float* W;
  unsigned short* WT;
  int N, n0, k0;
  if (bid < 768) {  // Wqkv: [1024][3072], 48 x 16 tiles
    W = Wqkv; WT = WqT; N = 3 * DM;
    n0 = (bid % 48) * 64; k0 = (bid / 48) * 64;
  } else {          // Wo: [1024][1024], 16 x 16 tiles
    bid -= 768;
    W = Wo; WT = WoT; N = DM;
    n0 = (bid % 16) * 64; k0 = (bid / 16) * 64;
  }
#pragma unroll
  for (int it = 0; it < 4; it++) {
    int row = it * 16 + (tid >> 4);
    int c4 = (tid & 15) * 4;
    f32x4 v = *(const f32x4*)&W[(size_t)(k0 + row) * N + n0 + c4];
#pragma unroll
    for (int j = 0; j < 4; j++) T[row][c4 + j] = v[j];
  }
  __syncthreads();
#pragma unroll
  for (int it = 0; it < 2; it++) {
    int chunk = tid + it * 256;
    int n = chunk >> 3;
    int c8 = (chunk & 7) * 8;
    uint4v s;
#pragma unroll
    for (int j = 0; j < 4; j++)
      s[j] = pack2bf(T[c8 + 2 * j][n], T[c8 + 2 * j + 1][n]);
    *(uint4v*)&WT[(size_t)(n0 + n) * DM + k0 + c8] = s;
  }
}

// ---------------------------------------------------------------------------
// 128x128 GEMM (round-3 proven form): C = A @ BT^T, fp32 accum. BK=64,
// 256 threads (4 waves 2x2), granule-XOR swizzle, single LDS buffer, two
// barriers per K-step. 32KB LDS -> 4-5 blocks/CU; cross-block TLP hides the
// staging latency (the r4 dbuf and r5/r6 256^2 ring both REGRESSED: dbuf cut
// occupancy, the 1-block/CU ring had no independent work to overlap stalls).
// __launch_bounds__(256,4) pins 4 blocks/CU (VGPR cap 512/wave, no spill).
// MODE 0: A fp32 (VALU cvt staging); QKV scatter epilogue (V transposed).
// MODE 2: A bf16 (DMA staging);      QKV scatter epilogue (V transposed).
// MODE 1: A bf16 (DMA staging);      fp32 row-major output (Wo GEMM).
// ---------------------------------------------------------------------------
template <int MODE>
__global__ __launch_bounds__(256, 4) void gemm_kernel(
    const void* __restrict__ Av, const unsigned short* __restrict__ BT,
    unsigned short* __restrict__ out0, unsigned short* __restrict__ out1,
    unsigned short* __restrict__ out2, float* __restrict__ outf,
    int M, int N, int K) {
  __shared__ unsigned short As[128][64];
  __shared__ unsigned short Bs[128][64];

  const int tid = threadIdx.x;
  const int wave = tid >> 6;
  const int lane = tid & 63;
  const int quad = lane >> 4;
  const int lc = lane & 15;
  const int wr = wave >> 1;
  const int wc = wave & 1;
  const int m0 = blockIdx.y * 128;
  const int n0 = blockIdx.x * 128;
  const int xsw = lc & 7;               // fragment-read swizzle key
  const int lr8 = lane >> 3;            // staging: row within 8-row group
  const int sgo = ((lane & 7) ^ (lr8 & 7)) * 8;  // swizzled source offset

  f32x4 acc[4][4];
#pragma unroll
  for (int i = 0; i < 4; i++)
#pragma unroll
    for (int j = 0; j < 4; j++) acc[i][j] = (f32x4){0.f, 0.f, 0.f, 0.f};

  for (int k0 = 0; k0 < K; k0 += 64) {
    // ---- Stage A tile (128 x 64) ----
    if (MODE == 0) {
      const float* A = (const float*)Av;
#pragma unroll
      for (int i = 0; i < 4; i++) {
        int chunk = tid + i * 256;      // 1024 granules
        int r = chunk >> 3;
        int g = chunk & 7;
        int scol = (g ^ (r & 7)) * 8;
        f32x4 v0 = *(const f32x4*)&A[(size_t)(m0 + r) * K + k0 + scol];
        f32x4 v1 = *(const f32x4*)&A[(size_t)(m0 + r) * K + k0 + scol + 4];
        uint4v s;
        s[0] = pack2bf(v0[0], v0[1]);
        s[1] = pack2bf(v0[2], v0[3]);
        s[2] = pack2bf(v1[0], v1[1]);
        s[3] = pack2bf(v1[2], v1[3]);
        *(uint4v*)&As[r][g * 8] = s;
      }
    } else {
      const unsigned short* A = (const unsigned short*)Av;
#pragma unroll
      for (int it = 0; it < 4; it++) {
        int rbase = wave * 32 + it * 8;  // 8 rows = 1 KB per instruction
        gload_lds16(&A[(size_t)(m0 + rbase + lr8) * K + k0 + sgo],
                    &As[rbase][0]);
      }
    }
    // ---- Stage B tile (128 n-rows x 64 k) ----
#pragma unroll
    for (int it = 0; it < 4; it++) {
      int rbase = wave * 32 + it * 8;
      gload_lds16(&BT[(size_t)(n0 + rbase + lr8) * K + k0 + sgo],
                  &Bs[rbase][0]);
    }
    __syncthreads();

#pragma unroll
    for (int kc = 0; kc < 2; kc++) {
      short8 aA[4], bB[4];
#pragma unroll
      for (int mt = 0; mt < 4; mt++)
        aA[mt] = *(const short8*)&As[wr * 64 + mt * 16 + lc]
                                    [((kc * 4 + quad) ^ xsw) * 8];
#pragma unroll
      for (int nt = 0; nt < 4; nt++)
        bB[nt] = *(const short8*)&Bs[wc * 64 + nt * 16 + lc]
                                    [((kc * 4 + quad) ^ xsw) * 8];
#pragma unroll
      for (int mt = 0; mt < 4; mt++)
#pragma unroll
        for (int nt = 0; nt < 4; nt++)
          acc[mt][nt] = __builtin_amdgcn_mfma_f32_16x16x32_bf16(
              aA[mt], bB[nt], acc[mt][nt], 0, 0, 0);
    }
    __syncthreads();
  }

  // Epilogue: C/D layout col=lane&15, row=quad*4+reg.
  const int c = n0 >> 10;  // QKV segment (block-uniform): 0=Q 1=K 2=V
#pragma unroll
  for (int mt = 0; mt < 4; mt++)
#pragma unroll
    for (int nt = 0; nt < 4; nt++) {
      int rb = m0 + wr * 64 + mt * 16 + quad * 4;  // 4 consecutive tokens
      int col = n0 + wc * 64 + nt * 16 + lc;
      if (MODE == 1) {
#pragma unroll
        for (int r = 0; r < 4; r++)
          outf[(size_t)(rb + r) * N + col] = acc[mt][nt][r];
      } else {
        int rem = col & 1023;
        int h = rem >> 6;
        int dd = rem & 63;
        int b = rb >> 11;
        int tt = rb & 2047;
        if (c == 2) {
          uint2v pk;
          pk[0] = pack2bf(acc[mt][nt][0], acc[mt][nt][1]);
          pk[1] = pack2bf(acc[mt][nt][2], acc[mt][nt][3]);
          *(uint2v*)&out2[(((size_t)(b * NH + h)) * DH + dd) * SEQ + tt] = pk;
        } else {
          unsigned short* dst = (c == 0) ? out0 : out1;
          float sc = (c == 0) ? QSCALE : 1.0f;
#pragma unroll
          for (int r = 0; r < 4; r++)
            dst[(((size_t)(b * NH + h) * SEQ + tt + r) << 6) + dd] =
                f2bf(acc[mt][nt][r] * sc);
        }
      }
    }
}

// ---------------------------------------------------------------------------
// Flash attention. Q,K: [bh][T][64] bf16 (Q pre-scaled); Vt: [bh][64][T] bf16.
// Block = 256 thr = 4 waves; wave owns 32 q-rows (block 128); 64-key tiles.
// S^T = K·Q^T via 32x32x16 MFMA -> 4 consecutive keys per lane. P packed by
// TRUNCATION; half-exchange via v_permlane32_swap_b32; l via MFMA ride-along
// (o_l = P·ones, same truncated fragments -> self-consistent). K/Vt
// double-buffered; XCD-aware grid (each XCD owns 8 heads; FETCH 24.6 MB).
// VGPR diet + __launch_bounds__(256,4) -> 56 VGPR, 84.5 us (round 3).
// ---------------------------------------------------------------------------
__global__ __launch_bounds__(256, 4) void attn_kernel(
    const unsigned short* __restrict__ Q, const unsigned short* __restrict__ K,
    const unsigned short* __restrict__ Vt, unsigned short* __restrict__ ctx) {
  __shared__ unsigned short KsL[2][64 * 64];  // granule-swizzled [key][d]
  __shared__ unsigned short VtL[2][64 * 64];  // granule-swizzled [d][key]

  const int tid = threadIdx.x;
  const int wave = tid >> 6;
  const int lane = tid & 63;
  const int half = lane >> 5;
  const int l31 = lane & 31;
  // XCD swizzle: dispatch order round-robins XCDs (id%8). Give each XCD 8
  // consecutive heads so all 16 q-tiles of a head share one L2.
  const int id = blockIdx.x;
  const int bh = (id & 7) * 8 + (id >> 3) / 16;
  const int qt = (id >> 3) & 15;
  const int q0 = qt * 128 + wave * 32;
  const unsigned kqbase = (unsigned)bh * (SEQ * DH);  // offsets fit 32-bit
  const unsigned vbase = (unsigned)bh * (DH * SEQ);

  // Q B-fragments (n=qrow=l31, k=d): 4 d-chunks of 16.
  short8 bQ[4];
#pragma unroll
  for (int dc = 0; dc < 4; dc++)
    bQ[dc] = *(const short8*)&Q[kqbase + (unsigned)(q0 + l31) * DH + dc * 16 + half * 8];

  f32x16 o[2], o_l;
#pragma unroll
  for (int nb = 0; nb < 2; nb++)
#pragma unroll
    for (int j = 0; j < 16; j++) o[nb][j] = 0.f;
#pragma unroll
  for (int j = 0; j < 16; j++) o_l[j] = 0.f;

  // All-ones bf16 B fragment for the l ride-along MFMA.
  union { unsigned u[4]; short8 s8; } onesu;
#pragma unroll
  for (int j = 0; j < 4; j++) onesu.u[j] = 0x3f803f80u;
  const short8 ones = onesu.s8;

  const int xsw = l31 & 7;  // bank-swizzle key for this lane's fragment rows
  // Hoisted staging geometry (granule id = wave*128 + it*64 + lane).
  // Second issue of each pair is +8 rows: same swizzle ((g0+64)&7 == g0&7,
  // (r0+8)&7 == r0&7) -> derive by constant add, no extra registers.
  const int g0 = wave * 128 + lane;
  const int r0 = g0 >> 3;
  const unsigned sgo = ((g0 & 7) ^ (r0 & 7)) * 8;
  const unsigned so0 = (unsigned)r0 * DH + sgo;
  const unsigned sv0 = (unsigned)r0 * SEQ + sgo;
  const int ldo = wave * 1024;  // this wave's staging region (shorts)

  auto stage = [&](int kt, int b) {
    const unsigned kg = kqbase + (unsigned)kt * (64 * DH);
    const unsigned vg = vbase + (unsigned)kt * 64;
    unsigned short* kd = &KsL[b][ldo];
    unsigned short* vd = &VtL[b][ldo];
    gload_lds16(&K[kg + so0], kd);
    gload_lds16(&K[kg + so0 + 8 * DH], kd + 512);
    gload_lds16(&Vt[vg + sv0], vd);
    gload_lds16(&Vt[vg + sv0 + 8 * SEQ], vd + 512);
  };

  stage(0, 0);
  __syncthreads();

  for (int kt = 0; kt < SEQ / 64; kt++) {
    const int cur = kt & 1;
    if (kt + 1 < SEQ / 64) stage(kt + 1, cur ^ 1);  // prefetch next tile
    const unsigned short* kcur = &KsL[cur][0];
    const unsigned short* vcur = &VtL[cur][0];

    // S^T = K·Q^T : two 32-key blocks, contraction d=64 (4 chained MFMA),
    // then softmax+pack and P·V for that key-block (in-register exchange).
#pragma unroll
    for (int kb = 0; kb < 2; kb++) {
      f32x16 s;
#pragma unroll
      for (int j = 0; j < 16; j++) s[j] = 0.f;
      __builtin_amdgcn_s_setprio(1);
#pragma unroll
      for (int dc = 0; dc < 4; dc++) {
        const short8 aK = *(const short8*)&kcur[(unsigned)(kb * 32 + l31) * 64 +
                                                ((dc * 2 + half) ^ xsw) * 8];
        s = __builtin_amdgcn_mfma_f32_32x32x16_bf16(aK, bQ[dc], s, 0, 0, 0);
      }
      __builtin_amdgcn_s_setprio(0);

      // p = exp2(s); truncate to bf16 (pack is 1 v_perm per pair).
      // Lane (l31,half) holds keys kb*32 + gq*8 + half*4 + {0..3} as packed
      // dwords d0[gq] (keys +0,1) and d1[gq] (keys +2,3).
      unsigned d0[4], d1[4];
#pragma unroll
      for (int gq = 0; gq < 4; gq++) {
        unsigned u0 = __float_as_uint(__builtin_amdgcn_exp2f(s[gq * 4 + 0]));
        unsigned u1 = __float_as_uint(__builtin_amdgcn_exp2f(s[gq * 4 + 1]));
        unsigned u2 = __float_as_uint(__builtin_amdgcn_exp2f(s[gq * 4 + 2]));
        unsigned u3 = __float_as_uint(__builtin_amdgcn_exp2f(s[gq * 4 + 3]));
        d0[gq] = pack2tr(u0, u1);
        d1[gq] = pack2tr(u2, u3);
      }

      // O += P·V for this 32-key block: chunks kc = kb*2 + {0,1}.
      // A-fragment dwords for chunk: w0..w3 = keys chunk*16 + half*8 + pairs.
      // v_permlane32_swap_b32 exchanges a.hi-lanes with b.lo-lanes:
      //   swap(d0[2k], d0[2k+1]) -> (w0, w2); swap(d1[2k], d1[2k+1]) -> (w1, w3).
      // l rides along as o_l = P·ones (same A fragments, same truncation ->
      // exactly self-consistent normalization, zero VALU cost).
#pragma unroll
      for (int kcl = 0; kcl < 2; kcl++) {
        unsigned w0 = d0[kcl * 2], w2 = d0[kcl * 2 + 1];
        unsigned w1 = d1[kcl * 2], w3 = d1[kcl * 2 + 1];
        asm("v_permlane32_swap_b32 %0, %1" : "+v"(w0), "+v"(w2));
        asm("v_permlane32_swap_b32 %0, %1" : "+v"(w1), "+v"(w3));
        union { unsigned u[4]; short8 s8; } cv;
        cv.u[0] = w0; cv.u[1] = w1; cv.u[2] = w2; cv.u[3] = w3;
        const int kc = kb * 2 + kcl;
        __builtin_amdgcn_s_setprio(1);
#pragma unroll
        for (int nb = 0; nb < 2; nb++) {
          const short8 bV = *(const short8*)&vcur[(unsigned)(nb * 32 + l31) * 64 +
                                                  ((kc * 2 + half) ^ xsw) * 8];
          o[nb] = __builtin_amdgcn_mfma_f32_32x32x16_bf16(cv.s8, bV, o[nb], 0, 0, 0);
        }
        o_l = __builtin_amdgcn_mfma_f32_32x32x16_bf16(cv.s8, ones, o_l, 0, 0, 0);
        __builtin_amdgcn_s_setprio(0);
      }
    }
    __syncthreads();  // staged next tile complete; buffers free for overwrite
  }

  // Epilogue: o_l rows align with o rows (same A-op, same MFMA shape), so
  // normalization is purely lane-local. ctx write coalesced over l31.
  const int b = bh >> 4;
  const int h = bh & 15;
#pragma unroll
  for (int gq = 0; gq < 4; gq++)
#pragma unroll
    for (int j = 0; j < 4; j++) {
      int r = gq * 4 + j;
      int ql = j + gq * 8 + half * 4;  // q within wave (C-layout row)
      float inv = __builtin_amdgcn_rcpf(o_l[r]);
      int token = qt * 128 + wave * 32 + ql;
#pragma unroll
      for (int nb = 0; nb < 2; nb++)
        ctx[((size_t)b * SEQ + token) * DM + h * DH + nb * 32 + l31] =
            f2bf(o[nb][r] * inv);
    }
}

extern "C" void kernel_launch(void* const* d_in, const int* in_sizes, int n_in,
                              void* d_out, int out_size, void* d_ws,
                              size_t ws_size, hipStream_t stream) {
  const float* x = (const float*)d_in[0];     // [8192,1024] fp32
  const float* Wqkv = (const float*)d_in[1];  // [1024,3072] fp32
  const float* Wo = (const float*)d_in[2];    // [1024,1024] fp32
  float* out = (float*)d_out;                 // [8192,1024] fp32
  unsigned short* ws = (unsigned short*)d_ws;

  unsigned short* Qb = ws;                          // [bh][T][64], pre-scaled
  unsigned short* Kb = ws + SEG;                    // [bh][T][64]
  unsigned short* Vt = ws + 2 * SEG;                // [bh][64][T]
  unsigned short* Ctx = ws + 3 * SEG;               // [8192][1024]
  unsigned short* WqT = Ctx + (size_t)MTOK * DM;    // [3072][1024]
  unsigned short* WoT = WqT + (size_t)3 * DM * DM;  // [1024][1024]
  unsigned short* Xb = WoT + (size_t)DM * DM;       // [8192][1024]
  const size_t need =
      ((size_t)(Xb - ws) + (size_t)MTOK * DM) * sizeof(unsigned short);

  if (ws_size >= need) {
    prep_kernel<true><<<dim3(4096 + 768 + 256), 256, 0, stream>>>(
        x, Xb, Wqkv, WqT, Wo, WoT);
    gemm_kernel<2><<<dim3(3 * DM / 128, MTOK / 128), 256, 0, stream>>>(
        (const void*)Xb, WqT, Qb, Kb, Vt, nullptr, MTOK, 3 * DM, DM);
  } else {
    prep_kernel<false><<<dim3(768 + 256), 256, 0, stream>>>(
        x, nullptr, Wqkv, WqT, Wo, WoT);
    gemm_kernel<0><<<dim3(3 * DM / 128, MTOK / 128), 256, 0, stream>>>(
        (const void*)x, WqT, Qb, Kb, Vt, nullptr, MTOK, 3 * DM, DM);
  }
  attn_kernel<<<dim3(SEQ / 128 * NBATCH * NH), 256, 0, stream>>>(Qb, Kb, Vt, Ctx);
  gemm_kernel<1><<<dim3(DM / 128, MTOK / 128), 256, 0, stream>>>(
      (const void*)Ctx, WoT, nullptr, nullptr, nullptr, out, MTOK, DM, DM);
}

// Round 8
// 256.834 us; speedup vs baseline: 1.0909x; 1.0111x over previous
//
#include <hip/hip_runtime.h>
#include <hip/hip_bf16.h>

typedef __attribute__((ext_vector_type(8))) short short8;
typedef __attribute__((ext_vector_type(4))) float f32x4;
typedef __attribute__((ext_vector_type(16))) float f32x16;
typedef __attribute__((ext_vector_type(2))) unsigned int uint2v;
typedef __attribute__((ext_vector_type(4))) unsigned int uint4v;

#define SEQ    2048
#define DM     1024
#define NH     16
#define DH     64
#define NBATCH 4
#define MTOK   (NBATCH * SEQ)                       // 8192 tokens
#define SEG    ((size_t)NBATCH * NH * SEQ * DH)     // 8388608 elems per Q/K/V buffer
// Q pre-scaled by 1/sqrt(64) * log2(e) so attention inner loop is exp2 only.
#define QSCALE 0.18033688f

// Fast RNE float->bf16 for FINITE values: bf16 bits land in the high 16.
static __device__ __forceinline__ unsigned bfbits(float f) {
  unsigned u = __float_as_uint(f);
  return u + 0x7fffu + ((u >> 16) & 1u);
}
static __device__ __forceinline__ unsigned short f2bf(float f) {
  return (unsigned short)(bfbits(f) >> 16);
}
// RNE pack of two floats to packed bf16x2 (lo in low half).
static __device__ __forceinline__ unsigned pack2bf(float lo, float hi) {
  return __builtin_amdgcn_perm(bfbits(hi), bfbits(lo), 0x07060302u);
}
// Truncation pack (round-toward-zero for positives): 1 v_perm on raw bits.
static __device__ __forceinline__ unsigned pack2tr(unsigned ulo, unsigned uhi) {
  return __builtin_amdgcn_perm(uhi, ulo, 0x07060302u);
}

typedef const __attribute__((address_space(1))) unsigned int* gp_t;
typedef __attribute__((address_space(3))) unsigned int* lp_t;
static __device__ __forceinline__ void gload_lds16(const void* g, void* l) {
  __builtin_amdgcn_global_load_lds((gp_t)g, (lp_t)l, 16, 0, 0);
}

// ---------------------------------------------------------------------------
// Fused prep: xcast (fp32->bf16, 8 elems/thread) + both weight transposes
// (W [K][N] fp32 -> WT [N][K] bf16, 64x64 tiles) in ONE dispatch.
// Block roles by blockIdx range: [0,4096) xcast, [4096,4864) Wqkv, rest Wo.
// ---------------------------------------------------------------------------
template <bool WITH_X>
__global__ __launch_bounds__(256) void prep_kernel(
    const float* __restrict__ x, unsigned short* __restrict__ xb,
    const float* __restrict__ Wqkv, unsigned short* __restrict__ WqT,
    const float* __restrict__ Wo, unsigned short* __restrict__ WoT) {
  __shared__ float T[64][65];
  const int tid = threadIdx.x;
  int bid = blockIdx.x;
  if (WITH_X) {
    if (bid < 4096) {
      size_t i = ((size_t)bid * 256 + tid) * 8;
      f32x4 a = *(const f32x4*)&x[i];
      f32x4 b = *(const f32x4*)&x[i + 4];
      uint4v s;
      s[0] = pack2bf(a[0], a[1]);
      s[1] = pack2bf(a[2], a[3]);
      s[2] = pack2bf(b[0], b[1]);
      s[3] = pack2bf(b[2], b[3]);
      *(uint4v*)&xb[i] = s;
      return;
    }
    bid -= 4096;
  }
  const float* W;
  unsigned short* WT;
  int N, n0, k0;
  if (bid < 768) {  // Wqkv: [1024][3072], 48 x 16 tiles
    W = Wqkv; WT = WqT; N = 3 * DM;
    n0 = (bid % 48) * 64; k0 = (bid / 48) * 64;
  } else {          // Wo: [1024][1024], 16 x 16 tiles
    bid -= 768;
    W = Wo; WT = WoT; N = DM;
    n0 = (bid % 16) * 64; k0 = (bid / 16) * 64;
  }
#pragma unroll
  for (int it = 0; it < 4; it++) {
    int row = it * 16 + (tid >> 4);
    int c4 = (tid & 15) * 4;
    f32x4 v = *(const f32x4*)&W[(size_t)(k0 + row) * N + n0 + c4];
#pragma unroll
    for (int j = 0; j < 4; j++) T[row][c4 + j] = v[j];
  }
  __syncthreads();
#pragma unroll
  for (int it = 0; it < 2; it++) {
    int chunk = tid + it * 256;
    int n = chunk >> 3;
    int c8 = (chunk & 7) * 8;
    uint4v s;
#pragma unroll
    for (int j = 0; j < 4; j++)
      s[j] = pack2bf(T[c8 + 2 * j][n], T[c8 + 2 * j + 1][n]);
    *(uint4v*)&WT[(size_t)(n0 + n) * DM + k0 + c8] = s;
  }
}

// ---------------------------------------------------------------------------
// 128x128 GEMM (round-3 proven form): C = A @ BT^T, fp32 accum. BK=64,
// 256 threads (4 waves 2x2), granule-XOR swizzle, single LDS buffer, two
// barriers per K-step. 32KB LDS -> 4 blocks/CU; cross-block TLP hides the
// staging latency.
// NEW (r8): 1D grid with bijective XCD decode — each XCD owns M/128/8
// contiguous m-bands with ALL n-blocks for those bands (A-panel stays in
// that XCD's L2; consecutive blocks share B-panels temporally). Same
// mechanism that cut attn FETCH 139->24.6 MB in r2. Requires (M/128)%8==0.
// MODE 0: A fp32 (VALU cvt staging); QKV scatter epilogue (V transposed).
// MODE 2: A bf16 (DMA staging);      QKV scatter epilogue (V transposed).
// MODE 1: A bf16 (DMA staging);      fp32 row-major output (Wo GEMM).
// ---------------------------------------------------------------------------
template <int MODE>
__global__ __launch_bounds__(256, 4) void gemm_kernel(
    const void* __restrict__ Av, const unsigned short* __restrict__ BT,
    unsigned short* __restrict__ out0, unsigned short* __restrict__ out1,
    unsigned short* __restrict__ out2, float* __restrict__ outf,
    int M, int N, int K) {
  __shared__ unsigned short As[128][64];
  __shared__ unsigned short Bs[128][64];

  const int tid = threadIdx.x;
  const int wave = tid >> 6;
  const int lane = tid & 63;
  const int quad = lane >> 4;
  const int lc = lane & 15;
  const int wr = wave >> 1;
  const int wc = wave & 1;
  // XCD-aware decode: xcd = id&7 (dispatch round-robins XCDs); within an
  // XCD, n varies fastest over that XCD's contiguous m-band chunk.
  const int id = blockIdx.x;
  const int nxb = N >> 7;                    // n-blocks
  const int mbx = (M >> 7) >> 3;             // m-bands per XCD
  const int idx = id >> 3;
  const int m0 = ((id & 7) * mbx + idx / nxb) * 128;
  const int n0 = (idx % nxb) * 128;
  const int xsw = lc & 7;               // fragment-read swizzle key
  const int lr8 = lane >> 3;            // staging: row within 8-row group
  const int sgo = ((lane & 7) ^ (lr8 & 7)) * 8;  // swizzled source offset

  f32x4 acc[4][4];
#pragma unroll
  for (int i = 0; i < 4; i++)
#pragma unroll
    for (int j = 0; j < 4; j++) acc[i][j] = (f32x4){0.f, 0.f, 0.f, 0.f};

  for (int k0 = 0; k0 < K; k0 += 64) {
    // ---- Stage A tile (128 x 64) ----
    if (MODE == 0) {
      const float* A = (const float*)Av;
#pragma unroll
      for (int i = 0; i < 4; i++) {
        int chunk = tid + i * 256;      // 1024 granules
        int r = chunk >> 3;
        int g = chunk & 7;
        int scol = (g ^ (r & 7)) * 8;
        f32x4 v0 = *(const f32x4*)&A[(size_t)(m0 + r) * K + k0 + scol];
        f32x4 v1 = *(const f32x4*)&A[(size_t)(m0 + r) * K + k0 + scol + 4];
        uint4v s;
        s[0] = pack2bf(v0[0], v0[1]);
        s[1] = pack2bf(v0[2], v0[3]);
        s[2] = pack2bf(v1[0], v1[1]);
        s[3] = pack2bf(v1[2], v1[3]);
        *(uint4v*)&As[r][g * 8] = s;
      }
    } else {
      const unsigned short* A = (const unsigned short*)Av;
#pragma unroll
      for (int it = 0; it < 4; it++) {
        int rbase = wave * 32 + it * 8;  // 8 rows = 1 KB per instruction
        gload_lds16(&A[(size_t)(m0 + rbase + lr8) * K + k0 + sgo],
                    &As[rbase][0]);
      }
    }
    // ---- Stage B tile (128 n-rows x 64 k) ----
#pragma unroll
    for (int it = 0; it < 4; it++) {
      int rbase = wave * 32 + it * 8;
      gload_lds16(&BT[(size_t)(n0 + rbase + lr8) * K + k0 + sgo],
                  &Bs[rbase][0]);
    }
    __syncthreads();

#pragma unroll
    for (int kc = 0; kc < 2; kc++) {
      short8 aA[4], bB[4];
#pragma unroll
      for (int mt = 0; mt < 4; mt++)
        aA[mt] = *(const short8*)&As[wr * 64 + mt * 16 + lc]
                                    [((kc * 4 + quad) ^ xsw) * 8];
#pragma unroll
      for (int nt = 0; nt < 4; nt++)
        bB[nt] = *(const short8*)&Bs[wc * 64 + nt * 16 + lc]
                                    [((kc * 4 + quad) ^ xsw) * 8];
#pragma unroll
      for (int mt = 0; mt < 4; mt++)
#pragma unroll
        for (int nt = 0; nt < 4; nt++)
          acc[mt][nt] = __builtin_amdgcn_mfma_f32_16x16x32_bf16(
              aA[mt], bB[nt], acc[mt][nt], 0, 0, 0);
    }
    __syncthreads();
  }

  // Epilogue: C/D layout col=lane&15, row=quad*4+reg.
  const int c = n0 >> 10;  // QKV segment (block-uniform): 0=Q 1=K 2=V
#pragma unroll
  for (int mt = 0; mt < 4; mt++)
#pragma unroll
    for (int nt = 0; nt < 4; nt++) {
      int rb = m0 + wr * 64 + mt * 16 + quad * 4;  // 4 consecutive tokens
      int col = n0 + wc * 64 + nt * 16 + lc;
      if (MODE == 1) {
#pragma unroll
        for (int r = 0; r < 4; r++)
          outf[(size_t)(rb + r) * N + col] = acc[mt][nt][r];
      } else {
        int rem = col & 1023;
        int h = rem >> 6;
        int dd = rem & 63;
        int b = rb >> 11;
        int tt = rb & 2047;
        if (c == 2) {
          uint2v pk;
          pk[0] = pack2bf(acc[mt][nt][0], acc[mt][nt][1]);
          pk[1] = pack2bf(acc[mt][nt][2], acc[mt][nt][3]);
          *(uint2v*)&out2[(((size_t)(b * NH + h)) * DH + dd) * SEQ + tt] = pk;
        } else {
          unsigned short* dst = (c == 0) ? out0 : out1;
          float sc = (c == 0) ? QSCALE : 1.0f;
#pragma unroll
          for (int r = 0; r < 4; r++)
            dst[(((size_t)(b * NH + h) * SEQ + tt + r) << 6) + dd] =
                f2bf(acc[mt][nt][r] * sc);
        }
      }
    }
}

// ---------------------------------------------------------------------------
// Flash attention. Q,K: [bh][T][64] bf16 (Q pre-scaled); Vt: [bh][64][T] bf16.
// Block = 256 thr = 4 waves; wave owns 32 q-rows (block 128); 64-key tiles.
// S^T = K·Q^T via 32x32x16 MFMA -> 4 consecutive keys per lane. P packed by
// TRUNCATION; half-exchange via v_permlane32_swap_b32; l via MFMA ride-along
// (o_l = P·ones, same truncated fragments -> self-consistent). K/Vt
// double-buffered; XCD-aware grid (each XCD owns 8 heads; FETCH 24.6 MB).
// VGPR diet + __launch_bounds__(256,4) -> 56 VGPR, 84.5 us (round 3).
// ---------------------------------------------------------------------------
__global__ __launch_bounds__(256, 4) void attn_kernel(
    const unsigned short* __restrict__ Q, const unsigned short* __restrict__ K,
    const unsigned short* __restrict__ Vt, unsigned short* __restrict__ ctx) {
  __shared__ unsigned short KsL[2][64 * 64];  // granule-swizzled [key][d]
  __shared__ unsigned short VtL[2][64 * 64];  // granule-swizzled [d][key]

  const int tid = threadIdx.x;
  const int wave = tid >> 6;
  const int lane = tid & 63;
  const int half = lane >> 5;
  const int l31 = lane & 31;
  // XCD swizzle: dispatch order round-robins XCDs (id%8). Give each XCD 8
  // consecutive heads so all 16 q-tiles of a head share one L2.
  const int id = blockIdx.x;
  const int bh = (id & 7) * 8 + (id >> 3) / 16;
  const int qt = (id >> 3) & 15;
  const int q0 = qt * 128 + wave * 32;
  const unsigned kqbase = (unsigned)bh * (SEQ * DH);  // offsets fit 32-bit
  const unsigned vbase = (unsigned)bh * (DH * SEQ);

  // Q B-fragments (n=qrow=l31, k=d): 4 d-chunks of 16.
  short8 bQ[4];
#pragma unroll
  for (int dc = 0; dc < 4; dc++)
    bQ[dc] = *(const short8*)&Q[kqbase + (unsigned)(q0 + l31) * DH + dc * 16 + half * 8];

  f32x16 o[2], o_l;
#pragma unroll
  for (int nb = 0; nb < 2; nb++)
#pragma unroll
    for (int j = 0; j < 16; j++) o[nb][j] = 0.f;
#pragma unroll
  for (int j = 0; j < 16; j++) o_l[j] = 0.f;

  // All-ones bf16 B fragment for the l ride-along MFMA.
  union { unsigned u[4]; short8 s8; } onesu;
#pragma unroll
  for (int j = 0; j < 4; j++) onesu.u[j] = 0x3f803f80u;
  const short8 ones = onesu.s8;

  const int xsw = l31 & 7;  // bank-swizzle key for this lane's fragment rows
  // Hoisted staging geometry (granule id = wave*128 + it*64 + lane).
  // Second issue of each pair is +8 rows: same swizzle ((g0+64)&7 == g0&7,
  // (r0+8)&7 == r0&7) -> derive by constant add, no extra registers.
  const int g0 = wave * 128 + lane;
  const int r0 = g0 >> 3;
  const unsigned sgo = ((g0 & 7) ^ (r0 & 7)) * 8;
  const unsigned so0 = (unsigned)r0 * DH + sgo;
  const unsigned sv0 = (unsigned)r0 * SEQ + sgo;
  const int ldo = wave * 1024;  // this wave's staging region (shorts)

  auto stage = [&](int kt, int b) {
    const unsigned kg = kqbase + (unsigned)kt * (64 * DH);
    const unsigned vg = vbase + (unsigned)kt * 64;
    unsigned short* kd = &KsL[b][ldo];
    unsigned short* vd = &VtL[b][ldo];
    gload_lds16(&K[kg + so0], kd);
    gload_lds16(&K[kg + so0 + 8 * DH], kd + 512);
    gload_lds16(&Vt[vg + sv0], vd);
    gload_lds16(&Vt[vg + sv0 + 8 * SEQ], vd + 512);
  };

  stage(0, 0);
  __syncthreads();

  for (int kt = 0; kt < SEQ / 64; kt++) {
    const int cur = kt & 1;
    if (kt + 1 < SEQ / 64) stage(kt + 1, cur ^ 1);  // prefetch next tile
    const unsigned short* kcur = &KsL[cur][0];
    const unsigned short* vcur = &VtL[cur][0];

    // S^T = K·Q^T : two 32-key blocks, contraction d=64 (4 chained MFMA),
    // then softmax+pack and P·V for that key-block (in-register exchange).
#pragma unroll
    for (int kb = 0; kb < 2; kb++) {
      f32x16 s;
#pragma unroll
      for (int j = 0; j < 16; j++) s[j] = 0.f;
      __builtin_amdgcn_s_setprio(1);
#pragma unroll
      for (int dc = 0; dc < 4; dc++) {
        const short8 aK = *(const short8*)&kcur[(unsigned)(kb * 32 + l31) * 64 +
                                                ((dc * 2 + half) ^ xsw) * 8];
        s = __builtin_amdgcn_mfma_f32_32x32x16_bf16(aK, bQ[dc], s, 0, 0, 0);
      }
      __builtin_amdgcn_s_setprio(0);

      // p = exp2(s); truncate to bf16 (pack is 1 v_perm per pair).
      // Lane (l31,half) holds keys kb*32 + gq*8 + half*4 + {0..3} as packed
      // dwords d0[gq] (keys +0,1) and d1[gq] (keys +2,3).
      unsigned d0[4], d1[4];
#pragma unroll
      for (int gq = 0; gq < 4; gq++) {
        unsigned u0 = __float_as_uint(__builtin_amdgcn_exp2f(s[gq * 4 + 0]));
        unsigned u1 = __float_as_uint(__builtin_amdgcn_exp2f(s[gq * 4 + 1]));
        unsigned u2 = __float_as_uint(__builtin_amdgcn_exp2f(s[gq * 4 + 2]));
        unsigned u3 = __float_as_uint(__builtin_amdgcn_exp2f(s[gq * 4 + 3]));
        d0[gq] = pack2tr(u0, u1);
        d1[gq] = pack2tr(u2, u3);
      }

      // O += P·V for this 32-key block: chunks kc = kb*2 + {0,1}.
      // A-fragment dwords for chunk: w0..w3 = keys chunk*16 + half*8 + pairs.
      // v_permlane32_swap_b32 exchanges a.hi-lanes with b.lo-lanes:
      //   swap(d0[2k], d0[2k+1]) -> (w0, w2); swap(d1[2k], d1[2k+1]) -> (w1, w3).
      // l rides along as o_l = P·ones (same A fragments, same truncation ->
      // exactly self-consistent normalization, zero VALU cost).
#pragma unroll
      for (int kcl = 0; kcl < 2; kcl++) {
        unsigned w0 = d0[kcl * 2], w2 = d0[kcl * 2 + 1];
        unsigned w1 = d1[kcl * 2], w3 = d1[kcl * 2 + 1];
        asm("v_permlane32_swap_b32 %0, %1" : "+v"(w0), "+v"(w2));
        asm("v_permlane32_swap_b32 %0, %1" : "+v"(w1), "+v"(w3));
        union { unsigned u[4]; short8 s8; } cv;
        cv.u[0] = w0; cv.u[1] = w1; cv.u[2] = w2; cv.u[3] = w3;
        const int kc = kb * 2 + kcl;
        __builtin_amdgcn_s_setprio(1);
#pragma unroll
        for (int nb = 0; nb < 2; nb++) {
          const short8 bV = *(const short8*)&vcur[(unsigned)(nb * 32 + l31) * 64 +
                                                  ((kc * 2 + half) ^ xsw) * 8];
          o[nb] = __builtin_amdgcn_mfma_f32_32x32x16_bf16(cv.s8, bV, o[nb], 0, 0, 0);
        }
        o_l = __builtin_amdgcn_mfma_f32_32x32x16_bf16(cv.s8, ones, o_l, 0, 0, 0);
        __builtin_amdgcn_s_setprio(0);
      }
    }
    __syncthreads();  // staged next tile complete; buffers free for overwrite
  }

  // Epilogue: o_l rows align with o rows (same A-op, same MFMA shape), so
  // normalization is purely lane-local. ctx write coalesced over l31.
  const int b = bh >> 4;
  const int h = bh & 15;
#pragma unroll
  for (int gq = 0; gq < 4; gq++)
#pragma unroll
    for (int j = 0; j < 4; j++) {
      int r = gq * 4 + j;
      int ql = j + gq * 8 + half * 4;  // q within wave (C-layout row)
      float inv = __builtin_amdgcn_rcpf(o_l[r]);
      int token = qt * 128 + wave * 32 + ql;
#pragma unroll
      for (int nb = 0; nb < 2; nb++)
        ctx[((size_t)b * SEQ + token) * DM + h * DH + nb * 32 + l31] =
            f2bf(o[nb][r] * inv);
    }
}

extern "C" void kernel_launch(void* const* d_in, const int* in_sizes, int n_in,
                              void* d_out, int out_size, void* d_ws,
                              size_t ws_size, hipStream_t stream) {
  const float* x = (const float*)d_in[0];     // [8192,1024] fp32
  const float* Wqkv = (const float*)d_in[1];  // [1024,3072] fp32
  const float* Wo = (const float*)d_in[2];    // [1024,1024] fp32
  float* out = (float*)d_out;                 // [8192,1024] fp32
  unsigned short* ws = (unsigned short*)d_ws;

  unsigned short* Qb = ws;                          // [bh][T][64], pre-scaled
  unsigned short* Kb = ws + SEG;                    // [bh][T][64]
  unsigned short* Vt = ws + 2 * SEG;                // [bh][64][T]
  unsigned short* Ctx = ws + 3 * SEG;               // [8192][1024]
  unsigned short* WqT = Ctx + (size_t)MTOK * DM;    // [3072][1024]
  unsigned short* WoT = WqT + (size_t)3 * DM * DM;  // [1024][1024]
  unsigned short* Xb = WoT + (size_t)DM * DM;       // [8192][1024]
  const size_t need =
      ((size_t)(Xb - ws) + (size_t)MTOK * DM) * sizeof(unsigned short);

  if (ws_size >= need) {
    prep_kernel<true><<<dim3(4096 + 768 + 256), 256, 0, stream>>>(
        x, Xb, Wqkv, WqT, Wo, WoT);
    gemm_kernel<2><<<dim3((3 * DM / 128) * (MTOK / 128)), 256, 0, stream>>>(
        (const void*)Xb, WqT, Qb, Kb, Vt, nullptr, MTOK, 3 * DM, DM);
  } else {
    prep_kernel<false><<<dim3(768 + 256), 256, 0, stream>>>(
        x, nullptr, Wqkv, WqT, Wo, WoT);
    gemm_kernel<0><<<dim3((3 * DM / 128) * (MTOK / 128)), 256, 0, stream>>>(
        (const void*)x, WqT, Qb, Kb, Vt, nullptr, MTOK, 3 * DM, DM);
  }
  attn_kernel<<<dim3(SEQ / 128 * NBATCH * NH), 256, 0, stream>>>(Qb, Kb, Vt, Ctx);
  gemm_kernel<1><<<dim3((DM / 128) * (MTOK / 128)), 256, 0, stream>>>(
      (const void*)Ctx, WoT, nullptr, nullptr, nullptr, out, MTOK, DM, DM);
}

// Round 10
// 253.109 us; speedup vs baseline: 1.1070x; 1.0147x over previous
//
#include <hip/hip_runtime.h>
#include <hip/hip_bf16.h>

typedef __attribute__((ext_vector_type(8))) short short8;
typedef __attribute__((ext_vector_type(4))) float f32x4;
typedef __attribute__((ext_vector_type(16))) float f32x16;
typedef __attribute__((ext_vector_type(2))) unsigned int uint2v;
typedef __attribute__((ext_vector_type(4))) unsigned int uint4v;

#define SEQ    2048
#define DM     1024
#define NH     16
#define DH     64
#define NBATCH 4
#define MTOK   (NBATCH * SEQ)                       // 8192 tokens
#define SEG    ((size_t)NBATCH * NH * SEQ * DH)     // 8388608 elems per Q/K/V buffer
// Q pre-scaled by 1/sqrt(64) * log2(e) so attention inner loop is exp2 only.
#define QSCALE 0.18033688f

// Fast RNE float->bf16 for FINITE values: bf16 bits land in the high 16.
static __device__ __forceinline__ unsigned bfbits(float f) {
  unsigned u = __float_as_uint(f);
  return u + 0x7fffu + ((u >> 16) & 1u);
}
static __device__ __forceinline__ unsigned short f2bf(float f) {
  return (unsigned short)(bfbits(f) >> 16);
}
// RNE pack of two floats to packed bf16x2 (lo in low half).
static __device__ __forceinline__ unsigned pack2bf(float lo, float hi) {
  return __builtin_amdgcn_perm(bfbits(hi), bfbits(lo), 0x07060302u);
}
// Truncation pack (round-toward-zero for positives): 1 v_perm on raw bits.
static __device__ __forceinline__ unsigned pack2tr(unsigned ulo, unsigned uhi) {
  return __builtin_amdgcn_perm(uhi, ulo, 0x07060302u);
}

typedef const __attribute__((address_space(1))) unsigned int* gp_t;
typedef __attribute__((address_space(3))) unsigned int* lp_t;
static __device__ __forceinline__ void gload_lds16(const void* g, void* l) {
  __builtin_amdgcn_global_load_lds((gp_t)g, (lp_t)l, 16, 0, 0);
}

// ---------------------------------------------------------------------------
// Fused prep: xcast (fp32->bf16, 8 elems/thread) + both weight transposes
// (W [K][N] fp32 -> WT [N][K] bf16, 64x64 tiles) in ONE dispatch.
// Block roles by blockIdx range: [0,4096) xcast, [4096,4864) Wqkv, rest Wo.
// ---------------------------------------------------------------------------
template <bool WITH_X>
__global__ __launch_bounds__(256) void prep_kernel(
    const float* __restrict__ x, unsigned short* __restrict__ xb,
    const float* __restrict__ Wqkv, unsigned short* __restrict__ WqT,
    const float* __restrict__ Wo, unsigned short* __restrict__ WoT) {
  __shared__ float T[64][65];
  const int tid = threadIdx.x;
  int bid = blockIdx.x;
  if (WITH_X) {
    if (bid < 4096) {
      size_t i = ((size_t)bid * 256 + tid) * 8;
      f32x4 a = *(const f32x4*)&x[i];
      f32x4 b = *(const f32x4*)&x[i + 4];
      uint4v s;
      s[0] = pack2bf(a[0], a[1]);
      s[1] = pack2bf(a[2], a[3]);
      s[2] = pack2bf(b[0], b[1]);
      s[3] = pack2bf(b[2], b[3]);
      *(uint4v*)&xb[i] = s;
      return;
    }
    bid -= 4096;
  }
  const float* W;
  unsigned short* WT;
  int N, n0, k0;
  if (bid < 768) {  // Wqkv: [1024][3072], 48 x 16 tiles
    W = Wqkv; WT = WqT; N = 3 * DM;
    n0 = (bid % 48) * 64; k0 = (bid / 48) * 64;
  } else {          // Wo: [1024][1024], 16 x 16 tiles
    bid -= 768;
    W = Wo; WT = WoT; N = DM;
    n0 = (bid % 16) * 64; k0 = (bid / 16) * 64;
  }
#pragma unroll
  for (int it = 0; it < 4; it++) {
    int row = it * 16 + (tid >> 4);
    int c4 = (tid & 15) * 4;
    f32x4 v = *(const f32x4*)&W[(size_t)(k0 + row) * N + n0 + c4];
#pragma unroll
    for (int j = 0; j < 4; j++) T[row][c4 + j] = v[j];
  }
  __syncthreads();
#pragma unroll
  for (int it = 0; it < 2; it++) {
    int chunk = tid + it * 256;
    int n = chunk >> 3;
    int c8 = (chunk & 7) * 8;
    uint4v s;
#pragma unroll
    for (int j = 0; j < 4; j++)
      s[j] = pack2bf(T[c8 + 2 * j][n], T[c8 + 2 * j + 1][n]);
    *(uint4v*)&WT[(size_t)(n0 + n) * DM + k0 + c8] = s;
  }
}

// ---------------------------------------------------------------------------
// 128xTN GEMM: C = A @ BT^T, fp32 accum. BK=64, 256 threads (4 waves),
// granule-XOR swizzle, single LDS buffer, two barriers per K-step, 1D grid
// with bijective XCD decode (each XCD owns contiguous m-bands).
// TN=128: 4 waves 2x2, wave tile 64x64, acc[4][4], 32KB LDS (QKV: 1536
//         blocks = 6/CU grid, 4/CU resident).
// TN=64:  4 waves 4x1, wave tile 32x64, acc[2][4], 24KB LDS. For the Wo
//         GEMM: N=1024 at TN=128 gives only 512 blocks = 2 blocks/CU ->
//         barrier drain exposed (r8 budget: Wo ~45us for 17.2GF). TN=64
//         doubles the grid to 1024 = 4 blocks/CU, restoring the cross-block
//         TLP this structure needs (r2->r3 attn lesson: 2->4 blocks/CU).
// MODE 0: A fp32 (VALU cvt staging); QKV scatter epilogue (V transposed).
// MODE 2: A bf16 (DMA staging);      QKV scatter epilogue (V transposed).
// MODE 1: A bf16 (DMA staging);      fp32 row-major output (Wo GEMM).
// ---------------------------------------------------------------------------
template <int MODE, int TN>
__global__ __launch_bounds__(256, 4) void gemm_kernel(
    const void* __restrict__ Av, const unsigned short* __restrict__ BT,
    unsigned short* __restrict__ out0, unsigned short* __restrict__ out1,
    unsigned short* __restrict__ out2, float* __restrict__ outf,
    int M, int N, int K) {
  constexpr int MT = (TN == 128) ? 4 : 2;  // m-frags per wave
  __shared__ unsigned short As[128][64];
  __shared__ unsigned short Bs[TN][64];

  const int tid = threadIdx.x;
  const int wave = tid >> 6;
  const int lane = tid & 63;
  const int quad = lane >> 4;
  const int lc = lane & 15;
  const int wr = (TN == 128) ? (wave >> 1) : wave;
  const int wc = (TN == 128) ? (wave & 1) : 0;
  // XCD-aware decode: xcd = id&7; within an XCD, n varies fastest over that
  // XCD's contiguous m-band chunk. Requires (M/128)%8==0.
  const int id = blockIdx.x;
  const int nxb = N / TN;                    // n-blocks
  const int mbx = (M >> 7) >> 3;             // m-bands per XCD
  const int idx = id >> 3;
  const int m0 = ((id & 7) * mbx + idx / nxb) * 128;
  const int n0 = (idx % nxb) * TN;
  const int xsw = lc & 7;               // fragment-read swizzle key
  const int lr8 = lane >> 3;            // staging: row within 8-row group
  const int sgo = ((lane & 7) ^ (lr8 & 7)) * 8;  // swizzled source offset

  f32x4 acc[MT][4];
#pragma unroll
  for (int i = 0; i < MT; i++)
#pragma unroll
    for (int j = 0; j < 4; j++) acc[i][j] = (f32x4){0.f, 0.f, 0.f, 0.f};

  for (int k0 = 0; k0 < K; k0 += 64) {
    // ---- Stage A tile (128 x 64) ----
    if (MODE == 0) {
      const float* A = (const float*)Av;
#pragma unroll
      for (int i = 0; i < 4; i++) {
        int chunk = tid + i * 256;      // 1024 granules
        int r = chunk >> 3;
        int g = chunk & 7;
        int scol = (g ^ (r & 7)) * 8;
        f32x4 v0 = *(const f32x4*)&A[(size_t)(m0 + r) * K + k0 + scol];
        f32x4 v1 = *(const f32x4*)&A[(size_t)(m0 + r) * K + k0 + scol + 4];
        uint4v s;
        s[0] = pack2bf(v0[0], v0[1]);
        s[1] = pack2bf(v0[2], v0[3]);
        s[2] = pack2bf(v1[0], v1[1]);
        s[3] = pack2bf(v1[2], v1[3]);
        *(uint4v*)&As[r][g * 8] = s;
      }
    } else {
      const unsigned short* A = (const unsigned short*)Av;
#pragma unroll
      for (int it = 0; it < 4; it++) {
        int rbase = wave * 32 + it * 8;  // 8 rows = 1 KB per instruction
        gload_lds16(&A[(size_t)(m0 + rbase + lr8) * K + k0 + sgo],
                    &As[rbase][0]);
      }
    }
    // ---- Stage B tile (TN n-rows x 64 k) ----
#pragma unroll
    for (int it = 0; it < TN / 32; it++) {
      int rbase = wave * (TN / 4) + it * 8;
      gload_lds16(&BT[(size_t)(n0 + rbase + lr8) * K + k0 + sgo],
                  &Bs[rbase][0]);
    }
    __syncthreads();

#pragma unroll
    for (int kc = 0; kc < 2; kc++) {
      short8 aA[MT], bB[4];
#pragma unroll
      for (int mt = 0; mt < MT; mt++)
        aA[mt] = *(const short8*)&As[wr * (MT * 16) + mt * 16 + lc]
                                    [((kc * 4 + quad) ^ xsw) * 8];
#pragma unroll
      for (int nt = 0; nt < 4; nt++)
        bB[nt] = *(const short8*)&Bs[wc * 64 + nt * 16 + lc]
                                    [((kc * 4 + quad) ^ xsw) * 8];
#pragma unroll
      for (int mt = 0; mt < MT; mt++)
#pragma unroll
        for (int nt = 0; nt < 4; nt++)
          acc[mt][nt] = __builtin_amdgcn_mfma_f32_16x16x32_bf16(
              aA[mt], bB[nt], acc[mt][nt], 0, 0, 0);
    }
    __syncthreads();
  }

  // Epilogue: C/D layout col=lane&15, row=quad*4+reg.
  const int c = n0 >> 10;  // QKV segment (block-uniform): 0=Q 1=K 2=V
#pragma unroll
  for (int mt = 0; mt < MT; mt++)
#pragma unroll
    for (int nt = 0; nt < 4; nt++) {
      int rb = m0 + wr * (MT * 16) + mt * 16 + quad * 4;  // 4 consec tokens
      int col = n0 + wc * 64 + nt * 16 + lc;
      if (MODE == 1) {
#pragma unroll
        for (int r = 0; r < 4; r++)
          outf[(size_t)(rb + r) * N + col] = acc[mt][nt][r];
      } else {
        int rem = col & 1023;
        int h = rem >> 6;
        int dd = rem & 63;
        int b = rb >> 11;
        int tt = rb & 2047;
        if (c == 2) {
          uint2v pk;
          pk[0] = pack2bf(acc[mt][nt][0], acc[mt][nt][1]);
          pk[1] = pack2bf(acc[mt][nt][2], acc[mt][nt][3]);
          *(uint2v*)&out2[(((size_t)(b * NH + h)) * DH + dd) * SEQ + tt] = pk;
        } else {
          unsigned short* dst = (c == 0) ? out0 : out1;
          float sc = (c == 0) ? QSCALE : 1.0f;
#pragma unroll
          for (int r = 0; r < 4; r++)
            dst[(((size_t)(b * NH + h) * SEQ + tt + r) << 6) + dd] =
                f2bf(acc[mt][nt][r] * sc);
        }
      }
    }
}

// ---------------------------------------------------------------------------
// Flash attention. Q,K: [bh][T][64] bf16 (Q pre-scaled); Vt: [bh][64][T] bf16.
// Block = 256 thr = 4 waves; wave owns 32 q-rows (block 128); 64-key tiles.
// S^T = K·Q^T via 32x32x16 MFMA -> 4 consecutive keys per lane. P packed by
// TRUNCATION; half-exchange via v_permlane32_swap_b32; l via MFMA ride-along
// (o_l = P·ones, same truncated fragments -> self-consistent). K/Vt
// double-buffered; XCD-aware grid (each XCD owns 8 heads; FETCH 24.6 MB).
// VGPR diet + __launch_bounds__(256,4) -> 56 VGPR, 84.5 us (round 3).
// ---------------------------------------------------------------------------
__global__ __launch_bounds__(256, 4) void attn_kernel(
    const unsigned short* __restrict__ Q, const unsigned short* __restrict__ K,
    const unsigned short* __restrict__ Vt, unsigned short* __restrict__ ctx) {
  __shared__ unsigned short KsL[2][64 * 64];  // granule-swizzled [key][d]
  __shared__ unsigned short VtL[2][64 * 64];  // granule-swizzled [d][key]

  const int tid = threadIdx.x;
  const int wave = tid >> 6;
  const int lane = tid & 63;
  const int half = lane >> 5;
  const int l31 = lane & 31;
  // XCD swizzle: dispatch order round-robins XCDs (id%8). Give each XCD 8
  // consecutive heads so all 16 q-tiles of a head share one L2.
  const int id = blockIdx.x;
  const int bh = (id & 7) * 8 + (id >> 3) / 16;
  const int qt = (id >> 3) & 15;
  const int q0 = qt * 128 + wave * 32;
  const unsigned kqbase = (unsigned)bh * (SEQ * DH);  // offsets fit 32-bit
  const unsigned vbase = (unsigned)bh * (DH * SEQ);

  // Q B-fragments (n=qrow=l31, k=d): 4 d-chunks of 16.
  short8 bQ[4];
#pragma unroll
  for (int dc = 0; dc < 4; dc++)
    bQ[dc] = *(const short8*)&Q[kqbase + (unsigned)(q0 + l31) * DH + dc * 16 + half * 8];

  f32x16 o[2], o_l;
#pragma unroll
  for (int nb = 0; nb < 2; nb++)
#pragma unroll
    for (int j = 0; j < 16; j++) o[nb][j] = 0.f;
#pragma unroll
  for (int j = 0; j < 16; j++) o_l[j] = 0.f;

  // All-ones bf16 B fragment for the l ride-along MFMA.
  union { unsigned u[4]; short8 s8; } onesu;
#pragma unroll
  for (int j = 0; j < 4; j++) onesu.u[j] = 0x3f803f80u;
  const short8 ones = onesu.s8;

  const int xsw = l31 & 7;  // bank-swizzle key for this lane's fragment rows
  // Hoisted staging geometry (granule id = wave*128 + it*64 + lane).
  // Second issue of each pair is +8 rows: same swizzle ((g0+64)&7 == g0&7,
  // (r0+8)&7 == r0&7) -> derive by constant add, no extra registers.
  const int g0 = wave * 128 + lane;
  const int r0 = g0 >> 3;
  const unsigned sgo = ((g0 & 7) ^ (r0 & 7)) * 8;
  const unsigned so0 = (unsigned)r0 * DH + sgo;
  const unsigned sv0 = (unsigned)r0 * SEQ + sgo;
  const int ldo = wave * 1024;  // this wave's staging region (shorts)

  auto stage = [&](int kt, int b) {
    const unsigned kg = kqbase + (unsigned)kt * (64 * DH);
    const unsigned vg = vbase + (unsigned)kt * 64;
    unsigned short* kd = &KsL[b][ldo];
    unsigned short* vd = &VtL[b][ldo];
    gload_lds16(&K[kg + so0], kd);
    gload_lds16(&K[kg + so0 + 8 * DH], kd + 512);
    gload_lds16(&Vt[vg + sv0], vd);
    gload_lds16(&Vt[vg + sv0 + 8 * SEQ], vd + 512);
  };

  stage(0, 0);
  __syncthreads();

  for (int kt = 0; kt < SEQ / 64; kt++) {
    const int cur = kt & 1;
    if (kt + 1 < SEQ / 64) stage(kt + 1, cur ^ 1);  // prefetch next tile
    const unsigned short* kcur = &KsL[cur][0];
    const unsigned short* vcur = &VtL[cur][0];

    // S^T = K·Q^T : two 32-key blocks, contraction d=64 (4 chained MFMA),
    // then softmax+pack and P·V for that key-block (in-register exchange).
#pragma unroll
    for (int kb = 0; kb < 2; kb++) {
      f32x16 s;
#pragma unroll
      for (int j = 0; j < 16; j++) s[j] = 0.f;
      __builtin_amdgcn_s_setprio(1);
#pragma unroll
      for (int dc = 0; dc < 4; dc++) {
        const short8 aK = *(const short8*)&kcur[(unsigned)(kb * 32 + l31) * 64 +
                                                ((dc * 2 + half) ^ xsw) * 8];
        s = __builtin_amdgcn_mfma_f32_32x32x16_bf16(aK, bQ[dc], s, 0, 0, 0);
      }
      __builtin_amdgcn_s_setprio(0);

      // p = exp2(s); truncate to bf16 (pack is 1 v_perm per pair).
      // Lane (l31,half) holds keys kb*32 + gq*8 + half*4 + {0..3} as packed
      // dwords d0[gq] (keys +0,1) and d1[gq] (keys +2,3).
      unsigned d0[4], d1[4];
#pragma unroll
      for (int gq = 0; gq < 4; gq++) {
        unsigned u0 = __float_as_uint(__builtin_amdgcn_exp2f(s[gq * 4 + 0]));
        unsigned u1 = __float_as_uint(__builtin_amdgcn_exp2f(s[gq * 4 + 1]));
        unsigned u2 = __float_as_uint(__builtin_amdgcn_exp2f(s[gq * 4 + 2]));
        unsigned u3 = __float_as_uint(__builtin_amdgcn_exp2f(s[gq * 4 + 3]));
        d0[gq] = pack2tr(u0, u1);
        d1[gq] = pack2tr(u2, u3);
      }

      // O += P·V for this 32-key block: chunks kc = kb*2 + {0,1}.
      // A-fragment dwords for chunk: w0..w3 = keys chunk*16 + half*8 + pairs.
      // v_permlane32_swap_b32 exchanges a.hi-lanes with b.lo-lanes:
      //   swap(d0[2k], d0[2k+1]) -> (w0, w2); swap(d1[2k], d1[2k+1]) -> (w1, w3).
      // l rides along as o_l = P·ones (same A fragments, same truncation ->
      // exactly self-consistent normalization, zero VALU cost).
#pragma unroll
      for (int kcl = 0; kcl < 2; kcl++) {
        unsigned w0 = d0[kcl * 2], w2 = d0[kcl * 2 + 1];
        unsigned w1 = d1[kcl * 2], w3 = d1[kcl * 2 + 1];
        asm("v_permlane32_swap_b32 %0, %1" : "+v"(w0), "+v"(w2));
        asm("v_permlane32_swap_b32 %0, %1" : "+v"(w1), "+v"(w3));
        union { unsigned u[4]; short8 s8; } cv;
        cv.u[0] = w0; cv.u[1] = w1; cv.u[2] = w2; cv.u[3] = w3;
        const int kc = kb * 2 + kcl;
        __builtin_amdgcn_s_setprio(1);
#pragma unroll
        for (int nb = 0; nb < 2; nb++) {
          const short8 bV = *(const short8*)&vcur[(unsigned)(nb * 32 + l31) * 64 +
                                                  ((kc * 2 + half) ^ xsw) * 8];
          o[nb] = __builtin_amdgcn_mfma_f32_32x32x16_bf16(cv.s8, bV, o[nb], 0, 0, 0);
        }
        o_l = __builtin_amdgcn_mfma_f32_32x32x16_bf16(cv.s8, ones, o_l, 0, 0, 0);
        __builtin_amdgcn_s_setprio(0);
      }
    }
    __syncthreads();  // staged next tile complete; buffers free for overwrite
  }

  // Epilogue: o_l rows align with o rows (same A-op, same MFMA shape), so
  // normalization is purely lane-local. ctx write coalesced over l31.
  const int b = bh >> 4;
  const int h = bh & 15;
#pragma unroll
  for (int gq = 0; gq < 4; gq++)
#pragma unroll
    for (int j = 0; j < 4; j++) {
      int r = gq * 4 + j;
      int ql = j + gq * 8 + half * 4;  // q within wave (C-layout row)
      float inv = __builtin_amdgcn_rcpf(o_l[r]);
      int token = qt * 128 + wave * 32 + ql;
#pragma unroll
      for (int nb = 0; nb < 2; nb++)
        ctx[((size_t)b * SEQ + token) * DM + h * DH + nb * 32 + l31] =
            f2bf(o[nb][r] * inv);
    }
}

extern "C" void kernel_launch(void* const* d_in, const int* in_sizes, int n_in,
                              void* d_out, int out_size, void* d_ws,
                              size_t ws_size, hipStream_t stream) {
  const float* x = (const float*)d_in[0];     // [8192,1024] fp32
  const float* Wqkv = (const float*)d_in[1];  // [1024,3072] fp32
  const float* Wo = (const float*)d_in[2];    // [1024,1024] fp32
  float* out = (float*)d_out;                 // [8192,1024] fp32
  unsigned short* ws = (unsigned short*)d_ws;

  unsigned short* Qb = ws;                          // [bh][T][64], pre-scaled
  unsigned short* Kb = ws + SEG;                    // [bh][T][64]
  unsigned short* Vt = ws + 2 * SEG;                // [bh][64][T]
  unsigned short* Ctx = ws + 3 * SEG;               // [8192][1024]
  unsigned short* WqT = Ctx + (size_t)MTOK * DM;    // [3072][1024]
  unsigned short* WoT = WqT + (size_t)3 * DM * DM;  // [1024][1024]
  unsigned short* Xb = WoT + (size_t)DM * DM;       // [8192][1024]
  const size_t need =
      ((size_t)(Xb - ws) + (size_t)MTOK * DM) * sizeof(unsigned short);

  if (ws_size >= need) {
    prep_kernel<true><<<dim3(4096 + 768 + 256), 256, 0, stream>>>(
        x, Xb, Wqkv, WqT, Wo, WoT);
    gemm_kernel<2, 128><<<dim3((3 * DM / 128) * (MTOK / 128)), 256, 0, stream>>>(
        (const void*)Xb, WqT, Qb, Kb, Vt, nullptr, MTOK, 3 * DM, DM);
  } else {
    prep_kernel<false><<<dim3(768 + 256), 256, 0, stream>>>(
        x, nullptr, Wqkv, WqT, Wo, WoT);
    gemm_kernel<0, 128><<<dim3((3 * DM / 128) * (MTOK / 128)), 256, 0, stream>>>(
        (const void*)x, WqT, Qb, Kb, Vt, nullptr, MTOK, 3 * DM, DM);
  }
  attn_kernel<<<dim3(SEQ / 128 * NBATCH * NH), 256, 0, stream>>>(Qb, Kb, Vt, Ctx);
  gemm_kernel<1, 64><<<dim3((DM / 64) * (MTOK / 128)), 256, 0, stream>>>(
      (const void*)Ctx, WoT, nullptr, nullptr, nullptr, out, MTOK, DM, DM);
}